// Round 5
// baseline (65.058 us; speedup 1.0000x reference)
//
#include <hip/hip_runtime.h>
#include <math.h>

#define CCH     128
#define HWTOK   4096
#define MROWS   512
#define THREADS 128   // 2 waves per block, 64 tokens per block

using short8  = __attribute__((ext_vector_type(8))) short;
using float16 = __attribute__((ext_vector_type(16))) float;
using f4      = __attribute__((ext_vector_type(4))) float;
using f2      = __attribute__((ext_vector_type(2))) float;
using i4      = __attribute__((ext_vector_type(4))) int;

__device__ __forceinline__ unsigned f2bf_rne(float f) {
    unsigned u = __builtin_bit_cast(unsigned, f);
    return (u + 0x7FFFu + ((u >> 16) & 1u)) >> 16;
}
__device__ __forceinline__ float fmax3(float a, float b, float c) {
    return fmaxf(fmaxf(a, b), c);   // clang fuses to v_max3_f32
}

// ---------------------------------------------------------------------------
// Prep: pre-normalized bf16 memory rows as MFMA A-fragments in ws.
// fid = (mt*8 + kstep)*64 + lane, lane = hi*32 + r5:
//   holds memory[mt*32 + r5][kstep*16 + hi*8 + j] * rinv(row), j = 0..7 (bf16)
// ---------------------------------------------------------------------------
__global__ __launch_bounds__(256) void frag_kernel(const float* __restrict__ mem,
                                                   i4* __restrict__ wsfrag) {
    int fid   = blockIdx.x * 256 + threadIdx.x;   // 0..8191
    int mt    = fid >> 9;
    int rem   = fid & 511;
    int kstep = rem >> 6;
    int l     = rem & 63;
    int hi    = l >> 5, r5 = l & 31;
    int row   = mt * 32 + r5;
    int k0    = kstep * 16 + hi * 8;

    const float* mr = mem + (size_t)row * CCH;
    float s = 0.f;
    #pragma unroll
    for (int c = 0; c < CCH; c += 4) {
        f4 v = *reinterpret_cast<const f4*>(mr + c);
        s += v.x * v.x + v.y * v.y + v.z * v.z + v.w * v.w;
    }
    float sc = 1.0f / fmaxf(sqrtf(s), 1e-12f);

    unsigned p[4];
    #pragma unroll
    for (int j = 0; j < 4; ++j) {
        unsigned lo   = f2bf_rne(mr[k0 + 2 * j]     * sc);
        unsigned hi16 = f2bf_rne(mr[k0 + 2 * j + 1] * sc);
        p[j] = lo | (hi16 << 16);
    }
    i4 o; o.x = p[0]; o.y = p[1]; o.z = p[2]; o.w = p[3];
    wsfrag[fid] = o;
}

// ---------------------------------------------------------------------------
// Main: 2048 blocks x 2 waves; wave owns 32 tokens (one 32x32 MFMA tile col).
// Hot loop: MAX ONLY. Epilogue is BLOCK-COOPERATIVE with every 256B L2 sector
// written entirely by one wave instruction (f4, 16 lanes x 16B contiguous) —
// r3/r4's half-sector-per-wave stores caused RMW write amplification
// (WRITE_SIZE 64->123 MB, FETCH +28 MB).
// ---------------------------------------------------------------------------
__global__ __launch_bounds__(THREADS, 4) void hardmem_mfma(
    const float* __restrict__ x, const float* __restrict__ mem,
    const i4* __restrict__ wsfrag, float* __restrict__ out)
{
    __shared__ int s_any;
    __shared__ int smask[64];
    __shared__ int sidx[64];

    const int tid  = threadIdx.x;
    const int wid  = tid >> 6;                 // 0..1
    const int lane = tid & 63;
    const int l5   = lane & 31, hi = lane >> 5;

    const int b    = blockIdx.x >> 6;                    // 64 blocks/batch
    const int tblk = (blockIdx.x & 63) * 64;             // block token base
    const int tb0  = tblk + wid * 32;                    // wave token base
    const float* xb = x + (size_t)b * CCH * HWTOK;

    if (tid == 0) s_any = 0;
    __syncthreads();

    // ---- build x B-fragment (token = tb0+l5); fp32 sum-of-squares on the fly
    short8 bf[8];
    float  s2;
    {
        const float* xt = xb + tb0 + l5;
        float s = 0.f;
        #pragma unroll
        for (int kstep = 0; kstep < 8; ++kstep) {
            const int c0 = kstep * 16 + hi * 8;
            float v[8];
            #pragma unroll
            for (int j = 0; j < 8; ++j) v[j] = xt[(size_t)(c0 + j) * HWTOK];
            unsigned p[4];
            #pragma unroll
            for (int j = 0; j < 4; ++j) {
                s = fmaf(v[2 * j],     v[2 * j],     s);
                s = fmaf(v[2 * j + 1], v[2 * j + 1], s);
                unsigned u0 = __builtin_bit_cast(unsigned, v[2 * j]);
                unsigned u1 = __builtin_bit_cast(unsigned, v[2 * j + 1]);
                p[j] = (u0 >> 16) | (u1 & 0xFFFF0000u);   // truncate-to-bf16
            }
            i4 pk; pk.x = p[0]; pk.y = p[1]; pk.z = p[2]; pk.w = p[3];
            bf[kstep] = __builtin_bit_cast(short8, pk);
        }
        s2 = s;
    }

    // ---- hot loop: max-only over 512 rows, A-frags double-buffered from L2
    const i4* wf = wsfrag + lane;
    float bmax = -1e30f;

    short8 afA[8], afB[8];
    #pragma unroll
    for (int k = 0; k < 8; ++k) afA[k] = __builtin_bit_cast(short8, wf[k * 64]);

    for (int mt = 0; mt < 16; mt += 2) {
        #pragma unroll
        for (int k = 0; k < 8; ++k)
            afB[k] = __builtin_bit_cast(short8, wf[((mt + 1) * 8 + k) * 64]);

        float16 acc;
        #pragma unroll
        for (int r = 0; r < 16; ++r) acc[r] = 0.f;
        #pragma unroll
        for (int k = 0; k < 8; ++k)
            acc = __builtin_amdgcn_mfma_f32_32x32x16_bf16(afA[k], bf[k], acc, 0, 0, 0);
        {
            float m0 = fmax3(acc[0], acc[1], acc[2]);
            float m1 = fmax3(acc[3], acc[4], acc[5]);
            float m2 = fmax3(acc[6], acc[7], acc[8]);
            float m3 = fmax3(acc[9], acc[10], acc[11]);
            float m4 = fmax3(acc[12], acc[13], acc[14]);
            bmax = fmaxf(bmax, fmax3(fmax3(m0, m1, m2), fmax3(m3, m4, acc[15]), bmax));
        }

        if (mt + 2 < 16) {
            #pragma unroll
            for (int k = 0; k < 8; ++k)
                afA[k] = __builtin_bit_cast(short8, wf[((mt + 2) * 8 + k) * 64]);
        }

        #pragma unroll
        for (int r = 0; r < 16; ++r) acc[r] = 0.f;
        #pragma unroll
        for (int k = 0; k < 8; ++k)
            acc = __builtin_amdgcn_mfma_f32_32x32x16_bf16(afB[k], bf[k], acc, 0, 0, 0);
        {
            float m0 = fmax3(acc[0], acc[1], acc[2]);
            float m1 = fmax3(acc[3], acc[4], acc[5]);
            float m2 = fmax3(acc[6], acc[7], acc[8]);
            float m3 = fmax3(acc[9], acc[10], acc[11]);
            float m4 = fmax3(acc[12], acc[13], acc[14]);
            bmax = fmaxf(bmax, fmax3(fmax3(m0, m1, m2), fmax3(m3, m4, acc[15]), bmax));
        }
    }

    // ---- threshold: bv/||x|| > 0.8  <=>  bv > 0.8*||x|| (norm > 0)
    bmax = fmaxf(bmax, __shfl_xor(bmax, 32));
    const float n2  = s2 + __shfl_xor(s2, 32);
    const bool  msk = bmax > 0.8f * fmaxf(sqrtf(n2), 1e-12f);

    unsigned long long wb = __ballot(msk);
    if (lane == 0 && wb != 0ULL) s_any = 1;
    __syncthreads();

    float* obase = out + (size_t)b * CCH * HWTOK;

    if (s_any == 0) {
        // ---- fast path: cooperative zero-fill, 64 tokens x 128 ch.
        // f4 stores: 16 lanes x 16B = one full 256B sector per instruction.
        const int tk4 = (tid & 15) * 4;      // token offset 0..60
        const int cb  = tid >> 4;            // 0..7
        f4 z = {0.f, 0.f, 0.f, 0.f};
        #pragma unroll
        for (int k = 0; k < 16; ++k) {
            int c = k * 8 + cb;
            *reinterpret_cast<f4*>(obase + (size_t)c * HWTOK + tblk + tk4) = z;
        }
    } else {
        // ---- rare path: per-wave argmax recompute (only if wave has a hit)
        int besti = 0;
        if (wb != 0ULL) {
            float bestv = -1e30f;
            for (int mt = 0; mt < 16; ++mt) {
                short8 af[8];
                #pragma unroll
                for (int k = 0; k < 8; ++k)
                    af[k] = __builtin_bit_cast(short8, wf[(mt * 8 + k) * 64]);
                float16 acc;
                #pragma unroll
                for (int r = 0; r < 16; ++r) acc[r] = 0.f;
                #pragma unroll
                for (int k = 0; k < 8; ++k)
                    acc = __builtin_amdgcn_mfma_f32_32x32x16_bf16(af[k], bf[k], acc, 0, 0, 0);
                const int rbase = mt * 32 + 4 * hi;
                #pragma unroll
                for (int r = 0; r < 16; ++r) {
                    // verified C/D map: row=(reg&3)+8*(reg>>2)+4*(lane>>5); ascending in r
                    const int row = rbase + (r & 3) + 8 * (r >> 2);
                    if (acc[r] > bestv) { bestv = acc[r]; besti = row; }
                }
            }
            float ov = __shfl_xor(bestv, 32);
            int   oi = __shfl_xor(besti, 32);
            if (ov > bestv || (ov == bestv && oi < besti)) { bestv = ov; besti = oi; }
        }
        if (hi == 0) {
            smask[wid * 32 + l5] = msk ? 1 : 0;
            sidx[wid * 32 + l5]  = besti;
        }
        __syncthreads();

        // cooperative masked-gather store, full 256B sectors per wave instr
        const int t2 = (tid & 31) * 2;       // token pair 0..62
        const int cq = tid >> 5;             // 0..3
        #pragma unroll 4
        for (int k = 0; k < 32; ++k) {
            int c = k * 4 + cq;
            float v0 = smask[t2]     ? mem[(size_t)sidx[t2]     * CCH + c] : 0.f;
            float v1 = smask[t2 + 1] ? mem[(size_t)sidx[t2 + 1] * CCH + c] : 0.f;
            f2 st; st.x = v0; st.y = v1;
            *reinterpret_cast<f2*>(obase + (size_t)c * HWTOK + tblk + t2) = st;
        }
    }
}

// ---------------------------------------------------------------------------
extern "C" void kernel_launch(void* const* d_in, const int* in_sizes, int n_in,
                              void* d_out, int out_size, void* d_ws, size_t ws_size,
                              hipStream_t stream) {
    const float* x   = (const float*)d_in[0];   // [32,128,64,64]
    const float* mem = (const float*)d_in[1];   // [512,128]
    float* out       = (float*)d_out;
    i4* wsfrag       = (i4*)d_ws;               // 128 KB fragment workspace

    frag_kernel<<<32, 256, 0, stream>>>(mem, wsfrag);
    hardmem_mfma<<<2048, THREADS, 0, stream>>>(x, mem, wsfrag, out);
}

// Round 6
// 64.973 us; speedup vs baseline: 1.0013x; 1.0013x over previous
//
#include <hip/hip_runtime.h>
#include <math.h>

#define CCH     128
#define HWTOK   4096
#define MROWS   512
#define THREADS 128   // 2 waves per block, 64 tokens per block

using short8  = __attribute__((ext_vector_type(8))) short;
using float16 = __attribute__((ext_vector_type(16))) float;
using f4      = __attribute__((ext_vector_type(4))) float;
using i4      = __attribute__((ext_vector_type(4))) int;

__device__ __forceinline__ unsigned f2bf_rne(float f) {
    unsigned u = __builtin_bit_cast(unsigned, f);
    return (u + 0x7FFFu + ((u >> 16) & 1u)) >> 16;
}
__device__ __forceinline__ float fmax3(float a, float b, float c) {
    return fmaxf(fmaxf(a, b), c);   // clang fuses to v_max3_f32
}

// ---------------------------------------------------------------------------
// Prep: pre-normalized bf16 memory rows as MFMA A-fragments in ws.
// fid = (mt*8 + kstep)*64 + lane, lane = hi*32 + r5:
//   holds memory[mt*32 + r5][kstep*16 + hi*8 + j] * rinv(row), j = 0..7 (bf16)
// ---------------------------------------------------------------------------
__global__ __launch_bounds__(256) void frag_kernel(const float* __restrict__ mem,
                                                   i4* __restrict__ wsfrag) {
    int fid   = blockIdx.x * 256 + threadIdx.x;   // 0..8191
    int mt    = fid >> 9;
    int rem   = fid & 511;
    int kstep = rem >> 6;
    int l     = rem & 63;
    int hi    = l >> 5, r5 = l & 31;
    int row   = mt * 32 + r5;
    int k0    = kstep * 16 + hi * 8;

    const float* mr = mem + (size_t)row * CCH;
    float s = 0.f;
    #pragma unroll
    for (int c = 0; c < CCH; c += 4) {
        f4 v = *reinterpret_cast<const f4*>(mr + c);
        s += v.x * v.x + v.y * v.y + v.z * v.z + v.w * v.w;
    }
    float sc = 1.0f / fmaxf(sqrtf(s), 1e-12f);

    unsigned p[4];
    #pragma unroll
    for (int j = 0; j < 4; ++j) {
        unsigned lo   = f2bf_rne(mr[k0 + 2 * j]     * sc);
        unsigned hi16 = f2bf_rne(mr[k0 + 2 * j + 1] * sc);
        p[j] = lo | (hi16 << 16);
    }
    i4 o; o.x = p[0]; o.y = p[1]; o.z = p[2]; o.w = p[3];
    wsfrag[fid] = o;
}

// ---------------------------------------------------------------------------
// Main: 2048 blocks x 2 waves; wave owns 32 tokens (one 32x32 MFMA tile col).
// Hot loop: MAX ONLY, A-frags double-buffered from L2.
// EPILOGUE: scalar-dword stores only (r1/r2 shape). Controlled experiment:
// every round using vector (>=8B) epilogue stores showed 1.9x WRITE_SIZE
// amplification (r3 nt-f4 124928, r4 f4 125952, r5 full-sector f4 121856 KB);
// both scalar-dword rounds were byte-exact 65536 KB. Per wave instruction:
// lanes 0..63 -> tokens tblk..tblk+63 at one channel = one full 256B sector.
// ---------------------------------------------------------------------------
__global__ __launch_bounds__(THREADS, 4) void hardmem_mfma(
    const float* __restrict__ x, const float* __restrict__ mem,
    const i4* __restrict__ wsfrag, float* __restrict__ out)
{
    __shared__ int s_any;
    __shared__ int smask[64];
    __shared__ int sidx[64];

    const int tid  = threadIdx.x;
    const int wid  = tid >> 6;                 // 0..1
    const int lane = tid & 63;
    const int l5   = lane & 31, hi = lane >> 5;

    const int b    = blockIdx.x >> 6;                    // 64 blocks/batch
    const int tblk = (blockIdx.x & 63) * 64;             // block token base
    const int tb0  = tblk + wid * 32;                    // wave token base
    const float* xb = x + (size_t)b * CCH * HWTOK;

    if (tid == 0) s_any = 0;
    __syncthreads();

    // ---- build x B-fragment (token = tb0+l5); fp32 sum-of-squares on the fly
    short8 bf[8];
    float  s2;
    {
        const float* xt = xb + tb0 + l5;
        float s = 0.f;
        #pragma unroll
        for (int kstep = 0; kstep < 8; ++kstep) {
            const int c0 = kstep * 16 + hi * 8;
            float v[8];
            #pragma unroll
            for (int j = 0; j < 8; ++j) v[j] = xt[(size_t)(c0 + j) * HWTOK];
            unsigned p[4];
            #pragma unroll
            for (int j = 0; j < 4; ++j) {
                s = fmaf(v[2 * j],     v[2 * j],     s);
                s = fmaf(v[2 * j + 1], v[2 * j + 1], s);
                unsigned u0 = __builtin_bit_cast(unsigned, v[2 * j]);
                unsigned u1 = __builtin_bit_cast(unsigned, v[2 * j + 1]);
                p[j] = (u0 >> 16) | (u1 & 0xFFFF0000u);   // truncate-to-bf16
            }
            i4 pk; pk.x = p[0]; pk.y = p[1]; pk.z = p[2]; pk.w = p[3];
            bf[kstep] = __builtin_bit_cast(short8, pk);
        }
        s2 = s;
    }

    // ---- hot loop: max-only over 512 rows, A-frags double-buffered from L2
    const i4* wf = wsfrag + lane;
    float bmax = -1e30f;

    short8 afA[8], afB[8];
    #pragma unroll
    for (int k = 0; k < 8; ++k) afA[k] = __builtin_bit_cast(short8, wf[k * 64]);

    for (int mt = 0; mt < 16; mt += 2) {
        #pragma unroll
        for (int k = 0; k < 8; ++k)
            afB[k] = __builtin_bit_cast(short8, wf[((mt + 1) * 8 + k) * 64]);

        float16 acc;
        #pragma unroll
        for (int r = 0; r < 16; ++r) acc[r] = 0.f;
        #pragma unroll
        for (int k = 0; k < 8; ++k)
            acc = __builtin_amdgcn_mfma_f32_32x32x16_bf16(afA[k], bf[k], acc, 0, 0, 0);
        {
            float m0 = fmax3(acc[0], acc[1], acc[2]);
            float m1 = fmax3(acc[3], acc[4], acc[5]);
            float m2 = fmax3(acc[6], acc[7], acc[8]);
            float m3 = fmax3(acc[9], acc[10], acc[11]);
            float m4 = fmax3(acc[12], acc[13], acc[14]);
            bmax = fmaxf(bmax, fmax3(fmax3(m0, m1, m2), fmax3(m3, m4, acc[15]), bmax));
        }

        if (mt + 2 < 16) {
            #pragma unroll
            for (int k = 0; k < 8; ++k)
                afA[k] = __builtin_bit_cast(short8, wf[((mt + 2) * 8 + k) * 64]);
        }

        #pragma unroll
        for (int r = 0; r < 16; ++r) acc[r] = 0.f;
        #pragma unroll
        for (int k = 0; k < 8; ++k)
            acc = __builtin_amdgcn_mfma_f32_32x32x16_bf16(afB[k], bf[k], acc, 0, 0, 0);
        {
            float m0 = fmax3(acc[0], acc[1], acc[2]);
            float m1 = fmax3(acc[3], acc[4], acc[5]);
            float m2 = fmax3(acc[6], acc[7], acc[8]);
            float m3 = fmax3(acc[9], acc[10], acc[11]);
            float m4 = fmax3(acc[12], acc[13], acc[14]);
            bmax = fmaxf(bmax, fmax3(fmax3(m0, m1, m2), fmax3(m3, m4, acc[15]), bmax));
        }
    }

    // ---- threshold: bv/||x|| > 0.8  <=>  bv > 0.8*||x|| (norm > 0)
    bmax = fmaxf(bmax, __shfl_xor(bmax, 32));
    const float n2  = s2 + __shfl_xor(s2, 32);
    const bool  msk = bmax > 0.8f * fmaxf(sqrtf(n2), 1e-12f);

    unsigned long long wb = __ballot(msk);
    if (lane == 0 && wb != 0ULL) s_any = 1;
    __syncthreads();

    float* obase = out + (size_t)b * CCH * HWTOK + tblk;

    if (s_any == 0) {
        // ---- fast path: zero-fill 64 tokens x 128 ch, SCALAR dword stores.
        // l = tid + k*128: c = l>>6 (wave0 even ch, wave1 odd ch), t = l&63.
        // One wave instruction = 64 consecutive dwords = one 256B sector.
        #pragma unroll 8
        for (int k = 0; k < 64; ++k) {
            int l = tid + k * THREADS;
            int c = l >> 6, t = l & 63;
            obase[(size_t)c * HWTOK + t] = 0.f;
        }
    } else {
        // ---- rare path: per-wave argmax recompute (only if wave has a hit)
        int besti = 0;
        if (wb != 0ULL) {
            float bestv = -1e30f;
            for (int mt = 0; mt < 16; ++mt) {
                short8 af[8];
                #pragma unroll
                for (int k = 0; k < 8; ++k)
                    af[k] = __builtin_bit_cast(short8, wf[(mt * 8 + k) * 64]);
                float16 acc;
                #pragma unroll
                for (int r = 0; r < 16; ++r) acc[r] = 0.f;
                #pragma unroll
                for (int k = 0; k < 8; ++k)
                    acc = __builtin_amdgcn_mfma_f32_32x32x16_bf16(af[k], bf[k], acc, 0, 0, 0);
                const int rbase = mt * 32 + 4 * hi;
                #pragma unroll
                for (int r = 0; r < 16; ++r) {
                    // verified C/D map: row=(reg&3)+8*(reg>>2)+4*(lane>>5); ascending in r
                    const int row = rbase + (r & 3) + 8 * (r >> 2);
                    if (acc[r] > bestv) { bestv = acc[r]; besti = row; }
                }
            }
            float ov = __shfl_xor(bestv, 32);
            int   oi = __shfl_xor(besti, 32);
            if (ov > bestv || (ov == bestv && oi < besti)) { bestv = ov; besti = oi; }
        }
        if (hi == 0) {
            smask[wid * 32 + l5] = msk ? 1 : 0;
            sidx[wid * 32 + l5]  = besti;
        }
        __syncthreads();

        // masked gather, same scalar-dword store shape
        #pragma unroll 8
        for (int k = 0; k < 64; ++k) {
            int l = tid + k * THREADS;
            int c = l >> 6, t = l & 63;
            float val = 0.f;
            if (smask[t]) val = mem[(size_t)sidx[t] * CCH + c];
            obase[(size_t)c * HWTOK + t] = val;
        }
    }
}

// ---------------------------------------------------------------------------
extern "C" void kernel_launch(void* const* d_in, const int* in_sizes, int n_in,
                              void* d_out, int out_size, void* d_ws, size_t ws_size,
                              hipStream_t stream) {
    const float* x   = (const float*)d_in[0];   // [32,128,64,64]
    const float* mem = (const float*)d_in[1];   // [512,128]
    float* out       = (float*)d_out;
    i4* wsfrag       = (i4*)d_ws;               // 128 KB fragment workspace

    frag_kernel<<<32, 256, 0, stream>>>(mem, wsfrag);
    hardmem_mfma<<<2048, THREADS, 0, stream>>>(x, mem, wsfrag, out);
}

// Round 7
// 39.313 us; speedup vs baseline: 1.6549x; 1.6527x over previous
//
#include <hip/hip_runtime.h>
#include <math.h>

#define CCH     128
#define HWTOK   4096
#define MROWS   512
#define THREADS 1024   // 16 waves per block; 256 blocks = 1 block per CU

using short8  = __attribute__((ext_vector_type(8))) short;
using float16 = __attribute__((ext_vector_type(16))) float;
using f4      = __attribute__((ext_vector_type(4))) float;
using i4      = __attribute__((ext_vector_type(4))) int;

__device__ __forceinline__ unsigned f2bf_rne(float f) {
    unsigned u = __builtin_bit_cast(unsigned, f);
    return (u + 0x7FFFu + ((u >> 16) & 1u)) >> 16;
}
__device__ __forceinline__ float fmax3(float a, float b, float c) {
    return fmaxf(fmaxf(a, b), c);   // clang fuses to v_max3_f32
}

// ---------------------------------------------------------------------------
// Prep: pre-normalized bf16 memory rows as MFMA A-fragments in ws.
// fid = (mt*8 + kstep)*64 + lane, lane = hi*32 + r5:
//   holds memory[mt*32 + r5][kstep*16 + hi*8 + j] * rinv(row), j = 0..7 (bf16)
// ---------------------------------------------------------------------------
__global__ __launch_bounds__(256) void frag_kernel(const float* __restrict__ mem,
                                                   i4* __restrict__ wsfrag) {
    int fid   = blockIdx.x * 256 + threadIdx.x;   // 0..8191
    int mt    = fid >> 9;
    int rem   = fid & 511;
    int kstep = rem >> 6;
    int l     = rem & 63;
    int hi    = l >> 5, r5 = l & 31;
    int row   = mt * 32 + r5;
    int k0    = kstep * 16 + hi * 8;

    const float* mr = mem + (size_t)row * CCH;
    float s = 0.f;
    #pragma unroll
    for (int c = 0; c < CCH; c += 4) {
        f4 v = *reinterpret_cast<const f4*>(mr + c);
        s += v.x * v.x + v.y * v.y + v.z * v.z + v.w * v.w;
    }
    float sc = 1.0f / fmaxf(sqrtf(s), 1e-12f);

    unsigned p[4];
    #pragma unroll
    for (int j = 0; j < 4; ++j) {
        unsigned lo   = f2bf_rne(mr[k0 + 2 * j]     * sc);
        unsigned hi16 = f2bf_rne(mr[k0 + 2 * j + 1] * sc);
        p[j] = lo | (hi16 << 16);
    }
    i4 o; o.x = p[0]; o.y = p[1]; o.z = p[2]; o.w = p[3];
    wsfrag[fid] = o;
}

// ---------------------------------------------------------------------------
// Main: 256 blocks x 16 waves (1024 thr). ENTIRE 128 KB fragment table staged
// in LDS once per block (kills the 512 MB per-wave L2 re-read stream that made
// r3-r6 latency-bound: all pipes <35% busy). After one barrier the hot loop is
// wave-independent: 16 mt x {8 ds_read_b128 + 8 MFMA + max-fold}. Wave owns 32
// tokens; max-only fast path; ballot-guarded exact argmax recompute (rare).
// ---------------------------------------------------------------------------
__global__ __launch_bounds__(THREADS, 4) void hardmem_mfma(
    const float* __restrict__ x, const float* __restrict__ mem,
    const i4* __restrict__ wsfrag, float* __restrict__ out)
{
    __shared__ i4 sfrag[8192];   // 128 KB — whole fragment table

    const int tid  = threadIdx.x;
    const int wid  = tid >> 6;                 // 0..15
    const int lane = tid & 63;
    const int l5   = lane & 31, hi = lane >> 5;

    const int b   = blockIdx.x >> 3;                     // 8 blocks/batch
    const int tb0 = (blockIdx.x & 7) * 512 + wid * 32;   // wave token base
    const float* xb = x + (size_t)b * CCH * HWTOK;

    // ---- stage fragment table -> LDS (coalesced dwordx4 + ds_write_b128)
    #pragma unroll
    for (int i = 0; i < 8; ++i) {
        int idx = tid + i * THREADS;           // 0..8191
        sfrag[idx] = wsfrag[idx];
    }

    // ---- build x B-fragment (token = tb0+l5); fp32 sum-of-squares on the fly
    short8 bf[8];
    float  s2;
    {
        const float* xt = xb + tb0 + l5;
        float s = 0.f;
        #pragma unroll
        for (int kstep = 0; kstep < 8; ++kstep) {
            const int c0 = kstep * 16 + hi * 8;
            float v[8];
            #pragma unroll
            for (int j = 0; j < 8; ++j) v[j] = xt[(size_t)(c0 + j) * HWTOK];
            unsigned p[4];
            #pragma unroll
            for (int j = 0; j < 4; ++j) {
                s = fmaf(v[2 * j],     v[2 * j],     s);
                s = fmaf(v[2 * j + 1], v[2 * j + 1], s);
                unsigned u0 = __builtin_bit_cast(unsigned, v[2 * j]);
                unsigned u1 = __builtin_bit_cast(unsigned, v[2 * j + 1]);
                p[j] = (u0 >> 16) | (u1 & 0xFFFF0000u);   // truncate-to-bf16
            }
            i4 pk; pk.x = p[0]; pk.y = p[1]; pk.z = p[2]; pk.w = p[3];
            bf[kstep] = __builtin_bit_cast(short8, pk);
        }
        s2 = s;
    }

    __syncthreads();   // LDS table ready; no further block-wide syncs needed

    // ---- hot loop: max-only over 512 rows, A-frags from LDS (~40 cyc)
    float bmax = -1e30f;
    for (int mt = 0; mt < 16; ++mt) {
        short8 af[8];
        #pragma unroll
        for (int k = 0; k < 8; ++k)
            af[k] = __builtin_bit_cast(short8, sfrag[(mt * 8 + k) * 64 + lane]);

        float16 acc;
        #pragma unroll
        for (int r = 0; r < 16; ++r) acc[r] = 0.f;
        #pragma unroll
        for (int k = 0; k < 8; ++k)
            acc = __builtin_amdgcn_mfma_f32_32x32x16_bf16(af[k], bf[k], acc, 0, 0, 0);

        float m0 = fmax3(acc[0], acc[1], acc[2]);
        float m1 = fmax3(acc[3], acc[4], acc[5]);
        float m2 = fmax3(acc[6], acc[7], acc[8]);
        float m3 = fmax3(acc[9], acc[10], acc[11]);
        float m4 = fmax3(acc[12], acc[13], acc[14]);
        bmax = fmaxf(bmax, fmax3(fmax3(m0, m1, m2), fmax3(m3, m4, acc[15]), bmax));
    }

    // ---- threshold: bv/||x|| > 0.8  <=>  bv > 0.8*||x|| (norm > 0)
    bmax = fmaxf(bmax, __shfl_xor(bmax, 32));
    const float n2  = s2 + __shfl_xor(s2, 32);
    const bool  msk = bmax > 0.8f * fmaxf(sqrtf(n2), 1e-12f);

    const unsigned long long wb = __ballot(msk);

    // wave-local epilogue: lane's token t = tb0 + (lane&31); per instruction
    // lanes 0..31 cover one full 128B line (32 tokens) at channel 2k,
    // lanes 32..63 the line at channel 2k+1.
    float* ob = out + (size_t)b * CCH * HWTOK;
    const int t     = tb0 + (lane & 31);
    const int chalf = lane >> 5;

    if (wb == 0ULL) {
        // ---- fast path: zero-fill this wave's 32 tokens x 128 channels
        #pragma unroll 8
        for (int k = 0; k < 64; ++k) {
            int c = chalf + 2 * k;
            ob[(size_t)c * HWTOK + t] = 0.f;
        }
    } else {
        // ---- rare path: exact argmax recompute (identical MFMAs), gather
        float bestv = -1e30f; int besti = 0;
        for (int mt = 0; mt < 16; ++mt) {
            short8 af[8];
            #pragma unroll
            for (int k = 0; k < 8; ++k)
                af[k] = __builtin_bit_cast(short8, sfrag[(mt * 8 + k) * 64 + lane]);
            float16 acc;
            #pragma unroll
            for (int r = 0; r < 16; ++r) acc[r] = 0.f;
            #pragma unroll
            for (int k = 0; k < 8; ++k)
                acc = __builtin_amdgcn_mfma_f32_32x32x16_bf16(af[k], bf[k], acc, 0, 0, 0);
            const int rbase = mt * 32 + 4 * hi;
            #pragma unroll
            for (int r = 0; r < 16; ++r) {
                // verified C/D map: row=(reg&3)+8*(reg>>2)+4*(lane>>5); ascending in r
                const int row = rbase + (r & 3) + 8 * (r >> 2);
                if (acc[r] > bestv) { bestv = acc[r]; besti = row; }
            }
        }
        float ov = __shfl_xor(bestv, 32);
        int   oi = __shfl_xor(besti, 32);
        if (ov > bestv || (ov == bestv && oi < besti)) { bestv = ov; besti = oi; }

        const float* mrow = mem + (size_t)besti * CCH;
        #pragma unroll 8
        for (int k = 0; k < 64; ++k) {
            int c = chalf + 2 * k;
            float val = msk ? mrow[c] : 0.f;
            ob[(size_t)c * HWTOK + t] = val;
        }
    }
}

// ---------------------------------------------------------------------------
extern "C" void kernel_launch(void* const* d_in, const int* in_sizes, int n_in,
                              void* d_out, int out_size, void* d_ws, size_t ws_size,
                              hipStream_t stream) {
    const float* x   = (const float*)d_in[0];   // [32,128,64,64]
    const float* mem = (const float*)d_in[1];   // [512,128]
    float* out       = (float*)d_out;
    i4* wsfrag       = (i4*)d_ws;               // 128 KB fragment workspace

    frag_kernel<<<32, 256, 0, stream>>>(mem, wsfrag);
    hardmem_mfma<<<256, THREADS, 0, stream>>>(x, mem, wsfrag, out);
}